// Round 4
// baseline (267.834 us; speedup 1.0000x reference)
//
#include <hip/hip_runtime.h>
#include <math.h>

// Problem constants (reference: x_l [16, 1, 1536, 1536] fp32, PATCH=3, ALPHA=1)
#define IMG_W 1536
#define IMG_H 1536
#define NIMG  16

typedef float f32x4 __attribute__((ext_vector_type(4)));

// out(h,w) = sum_k v_k*exp(-v_k) / sum_k exp(-v_k) over the 3x3 zero-padded
// neighborhood (the "-x^2" shift cancels in softmax; padded taps: e=1, ve=0).
//
// R8 change vs R6/R5: both register-pipeline structures (burst R5, stream R6)
// plateaued at 2.4-2.8 TB/s with 30-42% occupancy -- long-lived waves with
// dependent compute never kept enough bytes in flight. Everything measured at
// >6 TB/s on this machine (memsets, float4 copy) is the opposite shape: tiny
// per-thread state, ~100% occupancy, fast-churning waves. So: one f32x4 of
// output per thread, reload all 3 rows (L2/LLC absorb the 3x re-read at ~8
// TB/s << 34 TB/s), recompute exps (VALU was 75% idle), no pipelining. 288
// blocks/CU of backlog keeps every SIMD full.
__global__ __launch_bounds__(128, 8)
void WeightedAverage_55551107006568_kernel(const float* __restrict__ x,
                                           float* __restrict__ out) {
    const int tid = threadIdx.x;
    const int w0  = ((blockIdx.x << 7) + tid) << 2;  // first owned column
    const int h   = blockIdx.y;                      // output row
    const size_t plane = (size_t)blockIdx.z * ((size_t)IMG_H * IMG_W);
    const float* xp = x + plane + w0;
    float* op = out + plane;

    const bool lok = (w0 > 0);            // col w0-1 exists (only g==0 false)
    const bool rok = (w0 + 4 < IMG_W);    // col w0+4 exists (only last g false)
    // Branchless halo addressing: out-of-image halo reads redirect to rp[0]
    // (always in-bounds); values are zero-selected at compute time.
    const int offL = lok ? -4 : 0;        // byte offset of left halo
    const int offR = rok ? 16 : 0;        // byte offset of right halo

    const bool tv = (h > 0);              // top neighbor row exists
    const bool bv = (h < IMG_H - 1);      // bottom neighbor row exists
    const int hm = tv ? h - 1 : 0;        // clamped (value zero-selected below)
    const int hp = bv ? h + 1 : IMG_H - 1;

    const float* r0 = xp + (size_t)hm * IMG_W;
    const float* r1 = xp + (size_t)h  * IMG_W;
    const float* r2 = xp + (size_t)hp * IMG_W;

    // ---- issue all 9 loads back-to-back ----
    f32x4 m0 = *(const f32x4*)r0;
    float a0 = *(const float*)((const char*)r0 + offL);
    float b0 = *(const float*)((const char*)r0 + offR);
    f32x4 m1 = *(const f32x4*)r1;
    float a1 = *(const float*)((const char*)r1 + offL);
    float b1 = *(const float*)((const char*)r1 + offR);
    f32x4 m2 = *(const f32x4*)r2;
    float a2 = *(const float*)((const char*)r2 + offL);
    float b2 = *(const float*)((const char*)r2 + offR);
    __builtin_amdgcn_sched_barrier(0);

    // ---- zero-select pads (exp(-0)=1, v=0 is exactly the pad tap) ----
    if (!tv) { m0 = (f32x4){0.f, 0.f, 0.f, 0.f}; a0 = 0.f; b0 = 0.f; }
    if (!bv) { m2 = (f32x4){0.f, 0.f, 0.f, 0.f}; a2 = 0.f; b2 = 0.f; }
    if (!lok) { a0 = 0.f; a1 = 0.f; a2 = 0.f; }
    if (!rok) { b0 = 0.f; b1 = 0.f; b2 = 0.f; }

    // ---- per-row horizontal 3-sums, accumulate vertically ----
    f32x4 den = {0.f, 0.f, 0.f, 0.f};
    f32x4 num = {0.f, 0.f, 0.f, 0.f};
    {
        const f32x4 mr[3] = {m0, m1, m2};
        const float ha[3] = {a0, a1, a2};
        const float hb[3] = {b0, b1, b2};
#pragma unroll
        for (int i = 0; i < 3; ++i) {
            const f32x4 mm = mr[i];
            const float eL = __expf(-ha[i]), vL = ha[i] * eL;
            const float e0 = __expf(-mm.x),  v0 = mm.x * e0;
            const float e1 = __expf(-mm.y),  v1 = mm.y * e1;
            const float e2 = __expf(-mm.z),  v2 = mm.z * e2;
            const float e3 = __expf(-mm.w),  v3 = mm.w * e3;
            const float eR = __expf(-hb[i]), vR = hb[i] * eR;
            den.x += eL + e0 + e1;  num.x += vL + v0 + v1;
            den.y += e0 + e1 + e2;  num.y += v0 + v1 + v2;
            den.z += e1 + e2 + e3;  num.z += v1 + v2 + v3;
            den.w += e2 + e3 + eR;  num.w += v2 + v3 + vR;
        }
    }

    f32x4 o;
    o.x = __fdividef(num.x, den.x);
    o.y = __fdividef(num.y, den.y);
    o.z = __fdividef(num.z, den.z);
    o.w = __fdividef(num.w, den.w);
    // write-once output: nontemporal so it doesn't evict input from L2/L3
    __builtin_nontemporal_store(o, (f32x4*)(op + (size_t)h * IMG_W + w0));
}

extern "C" void kernel_launch(void* const* d_in, const int* in_sizes, int n_in,
                              void* d_out, int out_size, void* d_ws, size_t ws_size,
                              hipStream_t stream) {
    const float* x = (const float*)d_in[0];
    float* out = (float*)d_out;
    dim3 grid(IMG_W / (128 * 4), IMG_H, NIMG);   // (3, 1536, 16) = 73728 blocks
    dim3 block(128, 1, 1);
    WeightedAverage_55551107006568_kernel<<<grid, block, 0, stream>>>(x, out);
}

// Round 5
// 259.576 us; speedup vs baseline: 1.0318x; 1.0318x over previous
//
#include <hip/hip_runtime.h>
#include <math.h>

// Problem constants (reference: x_l [16, 1, 1536, 1536] fp32, PATCH=3, ALPHA=1)
#define IMG_W 1536
#define IMG_H 1536
#define NIMG  16
#define RPB   2                     // output rows per thread

typedef float f32x4 __attribute__((ext_vector_type(4)));

// out(h,w) = sum_k v_k*exp(-v_k) / sum_k exp(-v_k) over the 3x3 zero-padded
// neighborhood (the "-x^2" shift cancels in softmax; padded taps: e=1, ve=0).
//
// R9 change vs R8: R8 hit 82% occupancy / 4.06 TB/s but FETCH_SIZE blew up to
// 239.5 MB (2.7x input) -- the 3 blocks reading row r (y=r-1,r,r+1) are 3
// apart in linear bid and land on DIFFERENT per-XCD L2s, so every XCD
// re-fetched every row. Fix (a): flat grid + XCD-aware decode -- bid%8 = XCD,
// each XCD owns 2 images and sweeps y sequentially, so y-adjacent blocks (8
// apart in bid) share one L2 and row re-reads become L2 hits. Works for both
// round-robin and chunked XCD dispatch maps. Fix (b): RPB=2 -- the middle two
// rows' horizontal exp-sums are reused in registers for both output rows
// (4.5 -> 3 exp/px), heading off the VALU wall at ~60us. Per-thread state
// stays ~56 VGPR so launch_bounds(128,8) keeps the 100%-occupancy cap.
__global__ __launch_bounds__(128, 8)
void WeightedAverage_55551107006568_kernel(const float* __restrict__ x,
                                           float* __restrict__ out) {
    // ---- XCD-aware block decode (3 xblk x 768 yblk x 16 img = 36864) ----
    const int bid   = blockIdx.x;
    const int xcd   = bid & 7;
    const int chunk = bid >> 3;                 // 0..4607 within this XCD
    const int z     = (xcd << 1) + (chunk / 2304);   // 2 images per XCD
    const int rem   = chunk % 2304;             // 768 yblk * 3 xblk
    const int yb    = rem / 3;
    const int xb    = rem - yb * 3;
    const int h0    = yb << 1;                  // first output row
    const int w0    = ((xb << 7) + threadIdx.x) << 2;  // first owned column

    const size_t plane = (size_t)z * ((size_t)IMG_H * IMG_W);
    const float* xp = x + plane + w0;
    float* op = out + plane + w0;

    const bool lok = (w0 > 0);            // col w0-1 exists
    const bool rok = (w0 + 4 < IMG_W);    // col w0+4 exists
    // Branchless halo addressing: out-of-image halo reads redirect to rp[0]
    // (always in-bounds); values are zero-selected at compute time.
    const int offL = lok ? -4 : 0;
    const int offR = rok ? 16 : 0;

    const bool tv = (h0 > 0);             // row h0-1 exists
    const bool bv = (h0 + 2 < IMG_H);     // row h0+2 exists
    const int rt = tv ? h0 - 1 : 0;       // clamped (zero-selected below)
    const int rb = bv ? h0 + 2 : IMG_H - 1;

    const float* rp0 = xp + (size_t)rt * IMG_W;
    const float* rp1 = xp + (size_t)h0 * IMG_W;
    const float* rp2 = xp + (size_t)(h0 + 1) * IMG_W;
    const float* rp3 = xp + (size_t)rb * IMG_W;

    // ---- issue all 12 loads back-to-back ----
    f32x4 m0 = *(const f32x4*)rp0;
    float a0 = *(const float*)((const char*)rp0 + offL);
    float b0 = *(const float*)((const char*)rp0 + offR);
    f32x4 m1 = *(const f32x4*)rp1;
    float a1 = *(const float*)((const char*)rp1 + offL);
    float b1 = *(const float*)((const char*)rp1 + offR);
    f32x4 m2 = *(const f32x4*)rp2;
    float a2 = *(const float*)((const char*)rp2 + offL);
    float b2 = *(const float*)((const char*)rp2 + offR);
    f32x4 m3 = *(const f32x4*)rp3;
    float a3 = *(const float*)((const char*)rp3 + offL);
    float b3 = *(const float*)((const char*)rp3 + offR);
    __builtin_amdgcn_sched_barrier(0);

    // ---- zero-select pads (exp(-0)=1, v=0 is exactly the pad tap) ----
    if (!tv) { m0 = (f32x4){0.f, 0.f, 0.f, 0.f}; a0 = 0.f; b0 = 0.f; }
    if (!bv) { m3 = (f32x4){0.f, 0.f, 0.f, 0.f}; a3 = 0.f; b3 = 0.f; }
    if (!lok) { a0 = 0.f; a1 = 0.f; a2 = 0.f; a3 = 0.f; }
    if (!rok) { b0 = 0.f; b1 = 0.f; b2 = 0.f; b3 = 0.f; }

    // ---- per-row horizontal 3-sums (computed once, reused vertically) ----
    f32x4 he[4], hv[4];
    {
        const f32x4 mr[4] = {m0, m1, m2, m3};
        const float ha[4] = {a0, a1, a2, a3};
        const float hb[4] = {b0, b1, b2, b3};
#pragma unroll
        for (int i = 0; i < 4; ++i) {
            const f32x4 mm = mr[i];
            const float eL = __expf(-ha[i]), vL = ha[i] * eL;
            const float e0 = __expf(-mm.x),  v0 = mm.x * e0;
            const float e1 = __expf(-mm.y),  v1 = mm.y * e1;
            const float e2 = __expf(-mm.z),  v2 = mm.z * e2;
            const float e3 = __expf(-mm.w),  v3 = mm.w * e3;
            const float eR = __expf(-hb[i]), vR = hb[i] * eR;
            he[i] = (f32x4){eL + e0 + e1, e0 + e1 + e2, e1 + e2 + e3, e2 + e3 + eR};
            hv[i] = (f32x4){vL + v0 + v1, v0 + v1 + v2, v1 + v2 + v3, v2 + v3 + vR};
        }
    }

    // ---- vertical 3-sums: middle pair shared by both output rows ----
    const f32x4 ce = he[1] + he[2];
    const f32x4 cv = hv[1] + hv[2];
    const f32x4 den0 = ce + he[0], num0 = cv + hv[0];
    const f32x4 den1 = ce + he[3], num1 = cv + hv[3];

    f32x4 o0, o1;
#pragma unroll
    for (int p = 0; p < 4; ++p) {
        o0[p] = __fdividef(num0[p], den0[p]);
        o1[p] = __fdividef(num1[p], den1[p]);
    }
    // write-once output: nontemporal so it doesn't evict input from L2/L3
    __builtin_nontemporal_store(o0, (f32x4*)(op + (size_t)h0 * IMG_W));
    __builtin_nontemporal_store(o1, (f32x4*)(op + (size_t)(h0 + 1) * IMG_W));
}

extern "C" void kernel_launch(void* const* d_in, const int* in_sizes, int n_in,
                              void* d_out, int out_size, void* d_ws, size_t ws_size,
                              hipStream_t stream) {
    const float* x = (const float*)d_in[0];
    float* out = (float*)d_out;
    // flat grid: 3 xblk * 768 yblk * 16 img = 36864 blocks, decoded in-kernel
    dim3 grid(36864, 1, 1);
    dim3 block(128, 1, 1);
    WeightedAverage_55551107006568_kernel<<<grid, block, 0, stream>>>(x, out);
}

// Round 6
// 256.722 us; speedup vs baseline: 1.0433x; 1.0111x over previous
//
#include <hip/hip_runtime.h>
#include <math.h>

// Problem constants (reference: x_l [16, 1, 1536, 1536] fp32, PATCH=3, ALPHA=1)
#define IMG_W 1536
#define IMG_H 1536
#define NIMG  16
#define RPB   4                     // output rows per thread
#define NRW   (RPB + 2)             // loaded rows incl. vertical halo

typedef float f32x4 __attribute__((ext_vector_type(4)));

// out(h,w) = sum_k v_k*exp(-v_k) / sum_k exp(-v_k) over the 3x3 zero-padded
// neighborhood (the "-x^2" shift cancels in softmax; padded taps: e=1, ve=0).
//
// R10 change vs R9: across R0/R6/R8/R9 fetch varied 87-240 MB yet duration
// pinned at ~90-98us -- byte count is not binding; the ~4 TB/s effective cap
// tracks VMEM request count + per-wave latency budget. R9 spent 12 VMEM
// instrs/thread (half scalar-dword halos = 33% of requests for 3% of bytes)
// and 3 exp/px. This version: RPB=4 (fetch amp 1.5x, exp/px 2.25, 6 KB in
// flight per wave burst), halo e/v via __shfl from the neighbor lane's
// already-computed values (ds_permute, hidden by TLP) with real loads only on
// the 2 edge lanes -> ~8 VMEM instrs/thread. Keeps R8's fast-churn TLP shape
// and R9's XCD-aware decode (bid%8=XCD, 2 images/XCD, y swept sequentially so
// vertical-halo re-reads stay in one XCD's L2).
__global__ __launch_bounds__(128, 6)
void WeightedAverage_55551107006568_kernel(const float* __restrict__ x,
                                           float* __restrict__ out) {
    // ---- XCD-aware decode (3 xb * 384 yb * 16 img = 18432 blocks) ----
    const int bid   = blockIdx.x;
    const int xcd   = bid & 7;
    const int chunk = bid >> 3;                  // 0..2303 within this XCD
    const int z     = (xcd << 1) + (chunk / 1152);   // 2 images per XCD
    const int rem   = chunk % 1152;              // 384 yb * 3 xb
    const int yb    = rem / 3;
    const int xb    = rem - yb * 3;
    const int h0    = yb << 2;                   // first output row
    const int w0    = ((xb << 7) + threadIdx.x) << 2;  // first owned column

    const size_t plane = (size_t)z * ((size_t)IMG_H * IMG_W);
    const float* xp = x + plane + w0;
    float* op = out + plane + w0;

    const int lane = threadIdx.x & 63;
    // real halo loads only on the 2 wave-edge lanes (cross-wave neighbors);
    // interior lanes get halo e/v via shfl of values they compute anyway
    const bool doL = (lane == 0)  && (w0 > 0);
    const bool doR = (lane == 63) && (w0 + 4 < IMG_W);

    int roff[NRW];
#pragma unroll
    for (int i = 0; i < NRW; ++i) {
        int r = h0 - 1 + i;                      // block-uniform row index
        r = r < 0 ? 0 : (r >= IMG_H ? IMG_H - 1 : r);   // clamped; zero-sel below
        roff[i] = r * IMG_W;
    }

    // ---- issue all loads back-to-back (6 dwordx4 + edge-lane dwords) ----
    f32x4 m[NRW];
#pragma unroll
    for (int i = 0; i < NRW; ++i) m[i] = *(const f32x4*)(xp + roff[i]);
    float hl[NRW] = {0.f,0.f,0.f,0.f,0.f,0.f};
    float hr[NRW] = {0.f,0.f,0.f,0.f,0.f,0.f};
    if (doL) {
#pragma unroll
        for (int i = 0; i < NRW; ++i) hl[i] = xp[roff[i] - 1];
    }
    if (doR) {
#pragma unroll
        for (int i = 0; i < NRW; ++i) hr[i] = xp[roff[i] + 4];
    }
    __builtin_amdgcn_sched_barrier(0);

    // ---- zero-select out-of-image rows (pad tap: v=0 -> e=1, ve=0) ----
    if (h0 == 0) {
        m[0] = (f32x4){0.f,0.f,0.f,0.f}; hl[0] = 0.f; hr[0] = 0.f;
    }
    if (h0 + NRW - 2 >= IMG_H) {                 // only the last y-block
        m[NRW-1] = (f32x4){0.f,0.f,0.f,0.f}; hl[NRW-1] = 0.f; hr[NRW-1] = 0.f;
    }

    // ---- per row: horizontal 3-sums, accumulate into the <=3 outputs using it
    f32x4 den[RPB], num[RPB];
#pragma unroll
    for (int j = 0; j < RPB; ++j) {
        den[j] = (f32x4){0.f,0.f,0.f,0.f};
        num[j] = (f32x4){0.f,0.f,0.f,0.f};
    }
#pragma unroll
    for (int i = 0; i < NRW; ++i) {
        const f32x4 mm = m[i];
        const float e0 = __expf(-mm.x), v0 = mm.x * e0;
        const float e1 = __expf(-mm.y), v1 = mm.y * e1;
        const float e2 = __expf(-mm.z), v2 = mm.z * e2;
        const float e3 = __expf(-mm.w), v3 = mm.w * e3;
        // edge-lane halo values (hl/hr==0 elsewhere -> exp=1, unused via select)
        const float elh = __expf(-hl[i]), vlh = hl[i] * elh;
        const float erh = __expf(-hr[i]), vrh = hr[i] * erh;
        // interior halo: neighbor lane's boundary column, computed once there
        const float e3s = __shfl_up(e3, 1),   v3s = __shfl_up(v3, 1);
        const float e0s = __shfl_down(e0, 1), v0s = __shfl_down(v0, 1);
        const float eL = (lane == 0)  ? elh : e3s;
        const float vL = (lane == 0)  ? vlh : v3s;
        const float eR = (lane == 63) ? erh : e0s;
        const float vR = (lane == 63) ? vrh : v0s;
        const f32x4 he = {eL + e0 + e1, e0 + e1 + e2, e1 + e2 + e3, e2 + e3 + eR};
        const f32x4 hv = {vL + v0 + v1, v0 + v1 + v2, v1 + v2 + v3, v2 + v3 + vR};
#pragma unroll
        for (int j = 0; j < RPB; ++j)
            if (j <= i && i <= j + 2) { den[j] += he; num[j] += hv; }
    }

    // ---- divide + store (all RPB rows valid: grid divides exactly) ----
#pragma unroll
    for (int j = 0; j < RPB; ++j) {
        f32x4 o;
        o.x = __fdividef(num[j].x, den[j].x);
        o.y = __fdividef(num[j].y, den[j].y);
        o.z = __fdividef(num[j].z, den[j].z);
        o.w = __fdividef(num[j].w, den[j].w);
        // write-once output: nontemporal so it doesn't evict input from L2/L3
        __builtin_nontemporal_store(o, (f32x4*)(op + (size_t)(h0 + j) * IMG_W));
    }
}

extern "C" void kernel_launch(void* const* d_in, const int* in_sizes, int n_in,
                              void* d_out, int out_size, void* d_ws, size_t ws_size,
                              hipStream_t stream) {
    const float* x = (const float*)d_in[0];
    float* out = (float*)d_out;
    // flat grid: 3 xb * 384 yb * 16 img = 18432 blocks, decoded in-kernel
    dim3 grid(18432, 1, 1);
    dim3 block(128, 1, 1);
    WeightedAverage_55551107006568_kernel<<<grid, block, 0, stream>>>(x, out);
}

// Round 7
// 255.132 us; speedup vs baseline: 1.0498x; 1.0062x over previous
//
#include <hip/hip_runtime.h>
#include <math.h>

// Problem constants (reference: x_l [16, 1, 1536, 1536] fp32, PATCH=3, ALPHA=1)
#define IMG_W 1536
#define IMG_H 1536
#define NIMG  16
#define RPB   4                     // output rows per thread
#define NRW   (RPB + 2)             // loaded rows incl. vertical halo

typedef float f32x4 __attribute__((ext_vector_type(4)));

// out(h,w) = sum_k v_k*exp(-v_k) / sum_k exp(-v_k) over the 3x3 zero-padded
// neighborhood (the "-x^2" shift cancels in softmax; padded taps: e=1, ve=0).
//
// R11 change vs R10: SINGLE-VARIABLE ABLATION of the nontemporal store.
// Across R0/R6/R8/R10, fetch varied 74-240 MB, VALU-busy 25-50us, occupancy
// 29-82% -- and duration sat at 92-99us every time. The one invariant:
// WRITE_SIZE=147.5MB via __builtin_nontemporal_store (inherited, never
// ablated). 147.5MB/92us = 1.6 TB/s = 2.6 B/cy/CU -- consistent with a
// no-allocate write path that skips L2 write-combining, while the harness
// memsets push 6.6 TB/s through CACHED stores on this same buffer. Theory:
// every version was write-drain-bound; waves back up behind the store queue,
// which also inflated apparent read latency. This kernel is R10 with plain
// cached stores -- nothing else changed.
__global__ __launch_bounds__(128, 6)
void WeightedAverage_55551107006568_kernel(const float* __restrict__ x,
                                           float* __restrict__ out) {
    // ---- XCD-aware decode (3 xb * 384 yb * 16 img = 18432 blocks) ----
    const int bid   = blockIdx.x;
    const int xcd   = bid & 7;
    const int chunk = bid >> 3;                  // 0..2303 within this XCD
    const int z     = (xcd << 1) + (chunk / 1152);   // 2 images per XCD
    const int rem   = chunk % 1152;              // 384 yb * 3 xb
    const int yb    = rem / 3;
    const int xb    = rem - yb * 3;
    const int h0    = yb << 2;                   // first output row
    const int w0    = ((xb << 7) + threadIdx.x) << 2;  // first owned column

    const size_t plane = (size_t)z * ((size_t)IMG_H * IMG_W);
    const float* xp = x + plane + w0;
    float* op = out + plane + w0;

    const int lane = threadIdx.x & 63;
    // real halo loads only on the 2 wave-edge lanes (cross-wave neighbors);
    // interior lanes get halo e/v via shfl of values they compute anyway
    const bool doL = (lane == 0)  && (w0 > 0);
    const bool doR = (lane == 63) && (w0 + 4 < IMG_W);

    int roff[NRW];
#pragma unroll
    for (int i = 0; i < NRW; ++i) {
        int r = h0 - 1 + i;                      // block-uniform row index
        r = r < 0 ? 0 : (r >= IMG_H ? IMG_H - 1 : r);   // clamped; zero-sel below
        roff[i] = r * IMG_W;
    }

    // ---- issue all loads back-to-back (6 dwordx4 + edge-lane dwords) ----
    f32x4 m[NRW];
#pragma unroll
    for (int i = 0; i < NRW; ++i) m[i] = *(const f32x4*)(xp + roff[i]);
    float hl[NRW] = {0.f,0.f,0.f,0.f,0.f,0.f};
    float hr[NRW] = {0.f,0.f,0.f,0.f,0.f,0.f};
    if (doL) {
#pragma unroll
        for (int i = 0; i < NRW; ++i) hl[i] = xp[roff[i] - 1];
    }
    if (doR) {
#pragma unroll
        for (int i = 0; i < NRW; ++i) hr[i] = xp[roff[i] + 4];
    }
    __builtin_amdgcn_sched_barrier(0);

    // ---- zero-select out-of-image rows (pad tap: v=0 -> e=1, ve=0) ----
    if (h0 == 0) {
        m[0] = (f32x4){0.f,0.f,0.f,0.f}; hl[0] = 0.f; hr[0] = 0.f;
    }
    if (h0 + NRW - 2 >= IMG_H) {                 // only the last y-block
        m[NRW-1] = (f32x4){0.f,0.f,0.f,0.f}; hl[NRW-1] = 0.f; hr[NRW-1] = 0.f;
    }

    // ---- per row: horizontal 3-sums, accumulate into the <=3 outputs using it
    f32x4 den[RPB], num[RPB];
#pragma unroll
    for (int j = 0; j < RPB; ++j) {
        den[j] = (f32x4){0.f,0.f,0.f,0.f};
        num[j] = (f32x4){0.f,0.f,0.f,0.f};
    }
#pragma unroll
    for (int i = 0; i < NRW; ++i) {
        const f32x4 mm = m[i];
        const float e0 = __expf(-mm.x), v0 = mm.x * e0;
        const float e1 = __expf(-mm.y), v1 = mm.y * e1;
        const float e2 = __expf(-mm.z), v2 = mm.z * e2;
        const float e3 = __expf(-mm.w), v3 = mm.w * e3;
        // edge-lane halo values (hl/hr==0 elsewhere -> exp=1, unused via select)
        const float elh = __expf(-hl[i]), vlh = hl[i] * elh;
        const float erh = __expf(-hr[i]), vrh = hr[i] * erh;
        // interior halo: neighbor lane's boundary column, computed once there
        const float e3s = __shfl_up(e3, 1),   v3s = __shfl_up(v3, 1);
        const float e0s = __shfl_down(e0, 1), v0s = __shfl_down(v0, 1);
        const float eL = (lane == 0)  ? elh : e3s;
        const float vL = (lane == 0)  ? vlh : v3s;
        const float eR = (lane == 63) ? erh : e0s;
        const float vR = (lane == 63) ? vrh : v0s;
        const f32x4 he = {eL + e0 + e1, e0 + e1 + e2, e1 + e2 + e3, e2 + e3 + eR};
        const f32x4 hv = {vL + v0 + v1, v0 + v1 + v2, v1 + v2 + v3, v2 + v3 + vR};
#pragma unroll
        for (int j = 0; j < RPB; ++j)
            if (j <= i && i <= j + 2) { den[j] += he; num[j] += hv; }
    }

    // ---- divide + store (all RPB rows valid: grid divides exactly) ----
#pragma unroll
    for (int j = 0; j < RPB; ++j) {
        f32x4 o;
        o.x = __fdividef(num[j].x, den[j].x);
        o.y = __fdividef(num[j].y, den[j].y);
        o.z = __fdividef(num[j].z, den[j].z);
        o.w = __fdividef(num[j].w, den[j].w);
        // R11: plain cached store (ablating nontemporal -- see header comment)
        *(f32x4*)(op + (size_t)(h0 + j) * IMG_W) = o;
    }
}

extern "C" void kernel_launch(void* const* d_in, const int* in_sizes, int n_in,
                              void* d_out, int out_size, void* d_ws, size_t ws_size,
                              hipStream_t stream) {
    const float* x = (const float*)d_in[0];
    float* out = (float*)d_out;
    // flat grid: 3 xb * 384 yb * 16 img = 18432 blocks, decoded in-kernel
    dim3 grid(18432, 1, 1);
    dim3 block(128, 1, 1);
    WeightedAverage_55551107006568_kernel<<<grid, block, 0, stream>>>(x, out);
}